// Round 5
// baseline (426.299 us; speedup 1.0000x reference)
//
#include <hip/hip_runtime.h>

#define NODES 50000
#define NB ((NODES + 255) / 256)   // 196 scan blocks

typedef __attribute__((ext_vector_type(8))) short short8;
typedef __attribute__((ext_vector_type(4))) float f32x4;

__device__ __forceinline__ ushort f2bf(float f) {
    uint u = __float_as_uint(f);
    uint r = (u + 0x7fffu + ((u >> 16) & 1u)) >> 16;
    return (ushort)r;
}
__device__ __forceinline__ float bf2f(ushort u) {
    return __uint_as_float(((uint)u) << 16);
}

// ---------------- degree / CSR build ----------------

__global__ void k_count(const int* __restrict__ dst, int E, int* __restrict__ degcnt) {
    int e = blockIdx.x * blockDim.x + threadIdx.x;
    if (e < E) atomicAdd(&degcnt[dst[e]], 1);
}

// phase 1: per-block sum of 256 counts
__global__ void k_bsum(const int* __restrict__ cnt, int* __restrict__ bsum) {
    __shared__ int s[256];
    int t = threadIdx.x;
    int i = blockIdx.x * 256 + t;
    s[t] = (i < NODES) ? cnt[i] : 0;
    __syncthreads();
    for (int off = 128; off; off >>= 1) {
        if (t < off) s[t] += s[t + off];
        __syncthreads();
    }
    if (t == 0) bsum[blockIdx.x] = s[0];
}

// phase 2: one block scans the block sums (nb <= 256) -> exclusive offsets
__global__ void k_bscan(const int* __restrict__ bsum, int* __restrict__ boff, int nb) {
    __shared__ int s[256];
    int t = threadIdx.x;
    s[t] = (t < nb) ? bsum[t] : 0;
    __syncthreads();
    for (int off = 1; off < 256; off <<= 1) {
        int v = (t >= off) ? s[t - off] : 0;
        __syncthreads();
        s[t] += v;
        __syncthreads();
    }
    if (t < nb) boff[t] = (t == 0) ? 0 : s[t - 1];
}

// phase 3: per-block local exclusive scan + block offset; fused dinv
__global__ void k_scan3(const int* __restrict__ cnt, const int* __restrict__ boff,
                        int* __restrict__ rowstart, float* __restrict__ dinv) {
    __shared__ int s[256];
    int t = threadIdx.x;
    int i = blockIdx.x * 256 + t;
    int v = (i < NODES) ? cnt[i] : 0;
    s[t] = v;
    __syncthreads();
    for (int off = 1; off < 256; off <<= 1) {
        int u = (t >= off) ? s[t - off] : 0;
        __syncthreads();
        s[t] += u;
        __syncthreads();
    }
    if (i < NODES) {
        int excl = (t == 0) ? 0 : s[t - 1];
        rowstart[i] = boff[blockIdx.x] + excl;
        dinv[i] = rsqrtf(1.0f + (float)v);
        if (i == NODES - 1) rowstart[NODES] = boff[blockIdx.x] + s[t];
    }
}

// edge record: {src, bits(dinv[src])} -> one broadcast 8B load per edge later
__global__ void k_scatter(const int* __restrict__ src, const int* __restrict__ dst, int E,
                          const int* __restrict__ rowstart, int* __restrict__ cursor,
                          const float* __restrict__ dinv, int2* __restrict__ erec) {
    int e = blockIdx.x * blockDim.x + threadIdx.x;
    if (e < E) {
        int d = dst[e];
        int s = src[e];
        int p = atomicAdd(&cursor[d], 1);
        erec[rowstart[d] + p] = make_int2(s, __float_as_int(dinv[s]));
    }
}

// ---------------- casts ----------------

// in [R][C] f32 -> out [C][R] bf16 (transpose cast; weights only)
__global__ void k_castT(const float* __restrict__ in, ushort* __restrict__ out, int R, int C) {
    int i = blockIdx.x * blockDim.x + threadIdx.x;
    if (i >= R * C) return;
    int r = i / C, c = i % C;
    out[(size_t)c * R + r] = f2bf(in[i]);
}

// ---------------- bf16 MFMA GEMM: C[M,N] = A[M,K] @ Bt[N,K]^T ----------------
// BM=128; 256 threads = 4 waves. A either f32 (cast during staging) or bf16.
template <int BN, int WN, bool A_F32, bool OUTBF>
__global__ __launch_bounds__(256) void k_gemm_bf16(const float* __restrict__ Af,
                                                   const ushort* __restrict__ Ab,
                                                   const ushort* __restrict__ Bt,
                                                   float* __restrict__ C,
                                                   ushort* __restrict__ Cb,
                                                   int M, int N, int K) {
    constexpr int WM = 4 / WN;
    constexpr int WTM = 128 / WM;
    constexpr int WTN = BN / WN;
    constexpr int MT = WTM / 16;
    constexpr int NT = WTN / 16;
    constexpr int SA = 48;  // padded LDS row stride (elems)
    __shared__ ushort As[128 * SA];
    __shared__ ushort Bs[BN * SA];

    int t = threadIdx.x;
    int w = t >> 6, l = t & 63;
    int wm = w % WM, wn = w / WM;
    int bm = blockIdx.x * 128, bn = blockIdx.y * BN;
    int lr = l & 15, lk = (l >> 4) * 8;

    f32x4 acc[MT][NT] = {};
    const int ACH = 128 * 4;
    const int BCH = BN * 4;

    for (int k0 = 0; k0 < K; k0 += 32) {
        for (int c = t; c < ACH + BCH; c += 256) {
            if (c < ACH) {
                int row = c >> 2, seg = c & 3;
                int gr = bm + row;
                if (A_F32) {
                    ushort r[8] = {0, 0, 0, 0, 0, 0, 0, 0};
                    if (gr < M) {
                        float4 a = *(const float4*)(Af + (size_t)gr * K + k0 + seg * 8);
                        float4 b = *(const float4*)(Af + (size_t)gr * K + k0 + seg * 8 + 4);
                        r[0] = f2bf(a.x); r[1] = f2bf(a.y); r[2] = f2bf(a.z); r[3] = f2bf(a.w);
                        r[4] = f2bf(b.x); r[5] = f2bf(b.y); r[6] = f2bf(b.z); r[7] = f2bf(b.w);
                    }
                    *(int4*)(&As[row * SA + seg * 8]) = *(int4*)r;
                } else {
                    int4 v = make_int4(0, 0, 0, 0);
                    if (gr < M) v = *(const int4*)(Ab + (size_t)gr * K + k0 + seg * 8);
                    *(int4*)(&As[row * SA + seg * 8]) = v;
                }
            } else {
                int cc = c - ACH;
                int row = cc >> 2, seg = cc & 3;
                int4 v = *(const int4*)(Bt + (size_t)(bn + row) * K + k0 + seg * 8);
                *(int4*)(&Bs[row * SA + seg * 8]) = v;
            }
        }
        __syncthreads();
        short8 af[MT], bfr[NT];
#pragma unroll
        for (int mt = 0; mt < MT; ++mt)
            af[mt] = *(const short8*)(&As[(wm * WTM + mt * 16 + lr) * SA + lk]);
#pragma unroll
        for (int nt = 0; nt < NT; ++nt)
            bfr[nt] = *(const short8*)(&Bs[(wn * WTN + nt * 16 + lr) * SA + lk]);
#pragma unroll
        for (int mt = 0; mt < MT; ++mt)
#pragma unroll
            for (int nt = 0; nt < NT; ++nt)
                acc[mt][nt] = __builtin_amdgcn_mfma_f32_16x16x32_bf16(af[mt], bfr[nt], acc[mt][nt], 0, 0, 0);
        __syncthreads();
    }

#pragma unroll
    for (int mt = 0; mt < MT; ++mt)
#pragma unroll
        for (int nt = 0; nt < NT; ++nt)
#pragma unroll
            for (int i = 0; i < 4; ++i) {
                int row = bm + wm * WTM + mt * 16 + (l >> 4) * 4 + i;
                int col = bn + wn * WTN + nt * 16 + lr;
                if (row < M) {
                    float v = acc[mt][nt][i];
                    if (OUTBF) Cb[(size_t)row * N + col] = f2bf(v);
                    else       C[(size_t)row * N + col] = v;
                }
            }
}

// ---------------- layer-1 aggregation + bias + relu (bf16 in / bf16 out) ----------------
// one wave per node; lane l owns dims 4l..4l+3; edge loop unrolled x8 for MLP
__global__ __launch_bounds__(256) void k_agg1(const ushort* __restrict__ h,
                                              const int* __restrict__ rowstart,
                                              const int2* __restrict__ er,
                                              const float* __restrict__ dinv,
                                              const float* __restrict__ b1,
                                              ushort* __restrict__ out) {
    int wave = threadIdx.x >> 6;
    int lane = threadIdx.x & 63;
    int n = blockIdx.x * 4 + wave;
    if (n >= NODES) return;
    float4 acc = make_float4(0.f, 0.f, 0.f, 0.f);
    int e0 = rowstart[n], e1 = rowstart[n + 1];
    int e = e0;
#define A1_STEP(q, v)                                             \
    {                                                             \
        float w = __int_as_float((q).y);                          \
        acc.x = fmaf(w, bf2f((v).x), acc.x);                      \
        acc.y = fmaf(w, bf2f((v).y), acc.y);                      \
        acc.z = fmaf(w, bf2f((v).z), acc.z);                      \
        acc.w = fmaf(w, bf2f((v).w), acc.w);                      \
    }
    for (; e + 8 <= e1; e += 8) {
        int2 q0 = er[e],     q1 = er[e + 1], q2 = er[e + 2], q3 = er[e + 3];
        int2 q4 = er[e + 4], q5 = er[e + 5], q6 = er[e + 6], q7 = er[e + 7];
        ushort4 v0 = *(const ushort4*)(h + (size_t)q0.x * 256 + lane * 4);
        ushort4 v1 = *(const ushort4*)(h + (size_t)q1.x * 256 + lane * 4);
        ushort4 v2 = *(const ushort4*)(h + (size_t)q2.x * 256 + lane * 4);
        ushort4 v3 = *(const ushort4*)(h + (size_t)q3.x * 256 + lane * 4);
        ushort4 v4 = *(const ushort4*)(h + (size_t)q4.x * 256 + lane * 4);
        ushort4 v5 = *(const ushort4*)(h + (size_t)q5.x * 256 + lane * 4);
        ushort4 v6 = *(const ushort4*)(h + (size_t)q6.x * 256 + lane * 4);
        ushort4 v7 = *(const ushort4*)(h + (size_t)q7.x * 256 + lane * 4);
        A1_STEP(q0, v0) A1_STEP(q1, v1) A1_STEP(q2, v2) A1_STEP(q3, v3)
        A1_STEP(q4, v4) A1_STEP(q5, v5) A1_STEP(q6, v6) A1_STEP(q7, v7)
    }
    for (; e < e1; ++e) {
        int2 q = er[e];
        ushort4 v = *(const ushort4*)(h + (size_t)q.x * 256 + lane * 4);
        A1_STEP(q, v)
    }
#undef A1_STEP
    float dn = dinv[n];
    float s2 = dn * dn;
    ushort4 hv = *(const ushort4*)(h + (size_t)n * 256 + lane * 4);
    float4 bb = *(const float4*)(b1 + lane * 4);
    ushort4 r;
    r.x = f2bf(fmaxf(fmaf(acc.x, dn, fmaf(bf2f(hv.x), s2, bb.x)), 0.f));
    r.y = f2bf(fmaxf(fmaf(acc.y, dn, fmaf(bf2f(hv.y), s2, bb.y)), 0.f));
    r.z = f2bf(fmaxf(fmaf(acc.z, dn, fmaf(bf2f(hv.z), s2, bb.z)), 0.f));
    r.w = f2bf(fmaxf(fmaf(acc.w, dn, fmaf(bf2f(hv.w), s2, bb.w)), 0.f));
    *(ushort4*)(out + (size_t)n * 256 + lane * 4) = r;
}

// ---------------- layer-2 aggregation + bias + log_softmax (bf16 h2) ----------------
// one wave per node; lane l owns dim l (64 dims); unrolled x8
__global__ __launch_bounds__(256) void k_agg2(const ushort* __restrict__ h,
                                              const int* __restrict__ rowstart,
                                              const int2* __restrict__ er,
                                              const float* __restrict__ dinv,
                                              const float* __restrict__ b2,
                                              float* __restrict__ out) {
    int wave = threadIdx.x >> 6;
    int lane = threadIdx.x & 63;
    int n = blockIdx.x * 4 + wave;
    if (n >= NODES) return;
    float acc = 0.f;
    int e0 = rowstart[n], e1 = rowstart[n + 1];
    int e = e0;
    for (; e + 8 <= e1; e += 8) {
        int2 q0 = er[e],     q1 = er[e + 1], q2 = er[e + 2], q3 = er[e + 3];
        int2 q4 = er[e + 4], q5 = er[e + 5], q6 = er[e + 6], q7 = er[e + 7];
        ushort v0 = h[(size_t)q0.x * 64 + lane];
        ushort v1 = h[(size_t)q1.x * 64 + lane];
        ushort v2 = h[(size_t)q2.x * 64 + lane];
        ushort v3 = h[(size_t)q3.x * 64 + lane];
        ushort v4 = h[(size_t)q4.x * 64 + lane];
        ushort v5 = h[(size_t)q5.x * 64 + lane];
        ushort v6 = h[(size_t)q6.x * 64 + lane];
        ushort v7 = h[(size_t)q7.x * 64 + lane];
        acc = fmaf(__int_as_float(q0.y), bf2f(v0), acc);
        acc = fmaf(__int_as_float(q1.y), bf2f(v1), acc);
        acc = fmaf(__int_as_float(q2.y), bf2f(v2), acc);
        acc = fmaf(__int_as_float(q3.y), bf2f(v3), acc);
        acc = fmaf(__int_as_float(q4.y), bf2f(v4), acc);
        acc = fmaf(__int_as_float(q5.y), bf2f(v5), acc);
        acc = fmaf(__int_as_float(q6.y), bf2f(v6), acc);
        acc = fmaf(__int_as_float(q7.y), bf2f(v7), acc);
    }
    for (; e < e1; ++e) {
        int2 q = er[e];
        acc = fmaf(__int_as_float(q.y), bf2f(h[(size_t)q.x * 64 + lane]), acc);
    }
    float dn = dinv[n];
    float r = fmaf(acc, dn, fmaf(bf2f(h[(size_t)n * 64 + lane]), dn * dn, b2[lane]));
    float m = r;
#pragma unroll
    for (int off = 32; off; off >>= 1) m = fmaxf(m, __shfl_xor(m, off));
    float ex = __expf(r - m);
    float ssum = ex;
#pragma unroll
    for (int off = 32; off; off >>= 1) ssum += __shfl_xor(ssum, off);
    out[(size_t)n * 64 + lane] = r - m - __logf(ssum);
}

// ---------------- launch ----------------

extern "C" void kernel_launch(void* const* d_in, const int* in_sizes, int n_in,
                              void* d_out, int out_size, void* d_ws, size_t ws_size,
                              hipStream_t stream) {
    const float* x  = (const float*)d_in[0];
    const float* W1 = (const float*)d_in[1];
    const float* b1 = (const float*)d_in[2];
    const float* W2 = (const float*)d_in[3];
    const float* b2 = (const float*)d_in[4];
    const int*   ei = (const int*)d_in[5];
    int E = in_sizes[5] / 2;
    const int* src = ei;
    const int* dst = ei + E;
    float* out = (float*)d_out;

    char* wsp = (char*)d_ws;
    auto alloc = [&](size_t bytes) {
        char* p = wsp;
        wsp += (bytes + 255) & ~(size_t)255;
        return p;
    };
    int*    degcnt   = (int*)alloc((size_t)NODES * 4);
    float*  dinv     = (float*)alloc((size_t)NODES * 4);
    int*    rowstart = (int*)alloc((size_t)(NODES + 1) * 4);
    int*    cursor   = (int*)alloc((size_t)NODES * 4);
    int*    bsum     = (int*)alloc((size_t)NB * 4);
    int*    boff     = (int*)alloc((size_t)NB * 4);
    int2*   erec     = (int2*)alloc((size_t)E * 8);
    ushort* w1t      = (ushort*)alloc((size_t)256 * 512 * 2);   // W1^T bf16 [256][512]
    ushort* w2t      = (ushort*)alloc((size_t)64 * 256 * 2);    // W2^T bf16 [64][256]
    ushort* h1b      = (ushort*)alloc((size_t)NODES * 256 * 2); // bf16 h1
    ushort* h1ab     = (ushort*)alloc((size_t)NODES * 256 * 2); // bf16 relu(agg1)
    ushort* h2b      = (ushort*)alloc((size_t)NODES * 64 * 2);  // bf16 h2

    hipMemsetAsync(degcnt, 0, (size_t)NODES * 4, stream);
    hipMemsetAsync(cursor, 0, (size_t)NODES * 4, stream);

    k_count<<<(E + 255) / 256, 256, 0, stream>>>(dst, E, degcnt);
    k_bsum<<<NB, 256, 0, stream>>>(degcnt, bsum);
    k_bscan<<<1, 256, 0, stream>>>(bsum, boff, NB);
    k_scan3<<<NB, 256, 0, stream>>>(degcnt, boff, rowstart, dinv);
    k_scatter<<<(E + 255) / 256, 256, 0, stream>>>(src, dst, E, rowstart, cursor, dinv, erec);

    // weight casts (tiny)
    k_castT<<<(512 * 256 + 255) / 256, 256, 0, stream>>>(W1, w1t, 512, 256);
    k_castT<<<(256 * 64 + 255) / 256, 256, 0, stream>>>(W2, w2t, 256, 64);

    // layer 1: h1 = x @ W1  (A=f32 x, cast in staging) -> bf16
    k_gemm_bf16<128, 2, true, true><<<dim3((NODES + 127) / 128, 256 / 128), 256, 0, stream>>>(
        x, nullptr, w1t, nullptr, h1b, NODES, 256, 512);
    k_agg1<<<(NODES + 3) / 4, 256, 0, stream>>>(h1b, rowstart, erec, dinv, b1, h1ab);

    // layer 2: h2 = h1a @ W2 -> bf16
    k_gemm_bf16<64, 1, false, true><<<dim3((NODES + 127) / 128, 1), 256, 0, stream>>>(
        nullptr, h1ab, w2t, nullptr, h2b, NODES, 64, 256);
    k_agg2<<<(NODES + 3) / 4, 256, 0, stream>>>(h2b, rowstart, erec, dinv, b2, out);
}

// Round 6
// 373.835 us; speedup vs baseline: 1.1403x; 1.1403x over previous
//
#include <hip/hip_runtime.h>

#define NODES 50000
#define NB ((NODES + 255) / 256)   // 196 scan blocks

typedef __attribute__((ext_vector_type(8))) short short8;
typedef __attribute__((ext_vector_type(4))) float f32x4;
typedef __attribute__((ext_vector_type(2))) float f32x2;

__device__ __forceinline__ ushort f2bf(float f) {
    uint u = __float_as_uint(f);
    uint r = (u + 0x7fffu + ((u >> 16) & 1u)) >> 16;
    return (ushort)r;
}
__device__ __forceinline__ float bf2f(ushort u) {
    return __uint_as_float(((uint)u) << 16);
}
// HW OCP-e4m3 on gfx950: encode/decode both via VALU cvt -> self-consistent
__device__ __forceinline__ uchar f2fp8(float f) {
    return (uchar)(__builtin_amdgcn_cvt_pk_fp8_f32(f, f, 0, false) & 0xff);
}

// ---------------- degree / CSR build ----------------

__global__ void k_count(const int* __restrict__ dst, int E, int* __restrict__ degcnt) {
    int e = blockIdx.x * blockDim.x + threadIdx.x;
    if (e < E) atomicAdd(&degcnt[dst[e]], 1);
}

__global__ void k_bsum(const int* __restrict__ cnt, int* __restrict__ bsum) {
    __shared__ int s[256];
    int t = threadIdx.x;
    int i = blockIdx.x * 256 + t;
    s[t] = (i < NODES) ? cnt[i] : 0;
    __syncthreads();
    for (int off = 128; off; off >>= 1) {
        if (t < off) s[t] += s[t + off];
        __syncthreads();
    }
    if (t == 0) bsum[blockIdx.x] = s[0];
}

__global__ void k_bscan(const int* __restrict__ bsum, int* __restrict__ boff, int nb) {
    __shared__ int s[256];
    int t = threadIdx.x;
    s[t] = (t < nb) ? bsum[t] : 0;
    __syncthreads();
    for (int off = 1; off < 256; off <<= 1) {
        int v = (t >= off) ? s[t - off] : 0;
        __syncthreads();
        s[t] += v;
        __syncthreads();
    }
    if (t < nb) boff[t] = (t == 0) ? 0 : s[t - 1];
}

__global__ void k_scan3(const int* __restrict__ cnt, const int* __restrict__ boff,
                        int* __restrict__ rowstart, float* __restrict__ dinv) {
    __shared__ int s[256];
    int t = threadIdx.x;
    int i = blockIdx.x * 256 + t;
    int v = (i < NODES) ? cnt[i] : 0;
    s[t] = v;
    __syncthreads();
    for (int off = 1; off < 256; off <<= 1) {
        int u = (t >= off) ? s[t - off] : 0;
        __syncthreads();
        s[t] += u;
        __syncthreads();
    }
    if (i < NODES) {
        int excl = (t == 0) ? 0 : s[t - 1];
        rowstart[i] = boff[blockIdx.x] + excl;
        dinv[i] = rsqrtf(1.0f + (float)v);
        if (i == NODES - 1) rowstart[NODES] = boff[blockIdx.x] + s[t];
    }
}

__global__ void k_scatter(const int* __restrict__ src, const int* __restrict__ dst, int E,
                          const int* __restrict__ rowstart, int* __restrict__ cursor,
                          const float* __restrict__ dinv, int2* __restrict__ erec) {
    int e = blockIdx.x * blockDim.x + threadIdx.x;
    if (e < E) {
        int d = dst[e];
        int s = src[e];
        int p = atomicAdd(&cursor[d], 1);
        erec[rowstart[d] + p] = make_int2(s, __float_as_int(dinv[s]));
    }
}

// ---------------- casts ----------------

__global__ void k_castT(const float* __restrict__ in, ushort* __restrict__ out, int R, int C) {
    int i = blockIdx.x * blockDim.x + threadIdx.x;
    if (i >= R * C) return;
    int r = i / C, c = i % C;
    out[(size_t)c * R + r] = f2bf(in[i]);
}

// ---------------- bf16 MFMA GEMM: C[M,N] = A[M,K] @ Bt[N,K]^T ----------------
// 256 threads = 4 waves (WM x WN). A either f32 (cast in staging) or bf16.
// OUTMODE: 0 = f32, 1 = bf16, 2 = fp8-e4m3
template <int BM, int BN, int WM, int WN, bool A_F32, int OUTMODE>
__global__ __launch_bounds__(256) void k_gemm(const float* __restrict__ Af,
                                              const ushort* __restrict__ Ab,
                                              const ushort* __restrict__ Bt,
                                              float* __restrict__ C,
                                              ushort* __restrict__ Cb,
                                              uchar* __restrict__ C8,
                                              int M, int N, int K) {
    constexpr int WTM = BM / WM;
    constexpr int WTN = BN / WN;
    constexpr int MT = WTM / 16;
    constexpr int NT = WTN / 16;
    constexpr int SA = 48;  // padded LDS row stride (elems)
    __shared__ ushort As[BM * SA];
    __shared__ ushort Bs[BN * SA];

    int t = threadIdx.x;
    int w = t >> 6, l = t & 63;
    int wm = w % WM, wn = w / WM;
    int bm = blockIdx.x * BM, bn = blockIdx.y * BN;
    int lr = l & 15, lk = (l >> 4) * 8;

    f32x4 acc[MT][NT] = {};
    const int ACH = BM * 4;
    const int BCH = BN * 4;

    for (int k0 = 0; k0 < K; k0 += 32) {
        for (int c = t; c < ACH + BCH; c += 256) {
            if (c < ACH) {
                int row = c >> 2, seg = c & 3;
                int gr = bm + row;
                if (A_F32) {
                    ushort r[8] = {0, 0, 0, 0, 0, 0, 0, 0};
                    if (gr < M) {
                        float4 a = *(const float4*)(Af + (size_t)gr * K + k0 + seg * 8);
                        float4 b = *(const float4*)(Af + (size_t)gr * K + k0 + seg * 8 + 4);
                        r[0] = f2bf(a.x); r[1] = f2bf(a.y); r[2] = f2bf(a.z); r[3] = f2bf(a.w);
                        r[4] = f2bf(b.x); r[5] = f2bf(b.y); r[6] = f2bf(b.z); r[7] = f2bf(b.w);
                    }
                    *(int4*)(&As[row * SA + seg * 8]) = *(int4*)r;
                } else {
                    int4 v = make_int4(0, 0, 0, 0);
                    if (gr < M) v = *(const int4*)(Ab + (size_t)gr * K + k0 + seg * 8);
                    *(int4*)(&As[row * SA + seg * 8]) = v;
                }
            } else {
                int cc = c - ACH;
                int row = cc >> 2, seg = cc & 3;
                int4 v = *(const int4*)(Bt + (size_t)(bn + row) * K + k0 + seg * 8);
                *(int4*)(&Bs[row * SA + seg * 8]) = v;
            }
        }
        __syncthreads();
        short8 af[MT], bfr[NT];
#pragma unroll
        for (int mt = 0; mt < MT; ++mt)
            af[mt] = *(const short8*)(&As[(wm * WTM + mt * 16 + lr) * SA + lk]);
#pragma unroll
        for (int nt = 0; nt < NT; ++nt)
            bfr[nt] = *(const short8*)(&Bs[(wn * WTN + nt * 16 + lr) * SA + lk]);
#pragma unroll
        for (int mt = 0; mt < MT; ++mt)
#pragma unroll
            for (int nt = 0; nt < NT; ++nt)
                acc[mt][nt] = __builtin_amdgcn_mfma_f32_16x16x32_bf16(af[mt], bfr[nt], acc[mt][nt], 0, 0, 0);
        __syncthreads();
    }

#pragma unroll
    for (int mt = 0; mt < MT; ++mt)
#pragma unroll
        for (int nt = 0; nt < NT; ++nt)
#pragma unroll
            for (int i = 0; i < 4; ++i) {
                int row = bm + wm * WTM + mt * 16 + (l >> 4) * 4 + i;
                int col = bn + wn * WTN + nt * 16 + lr;
                if (row < M) {
                    float v = acc[mt][nt][i];
                    if (OUTMODE == 0) C[(size_t)row * N + col] = v;
                    else if (OUTMODE == 1) Cb[(size_t)row * N + col] = f2bf(v);
                    else C8[(size_t)row * N + col] = f2fp8(v);
                }
            }
}

// ---------------- layer-1 aggregation + bias + relu (fp8 in / bf16 out) ----------------
// one wave per node; lane l owns dims 4l..4l+3; unrolled x8
__global__ __launch_bounds__(256) void k_agg1(const uchar* __restrict__ h8,
                                              const int* __restrict__ rowstart,
                                              const int2* __restrict__ er,
                                              const float* __restrict__ dinv,
                                              const float* __restrict__ b1,
                                              ushort* __restrict__ out) {
    int wave = threadIdx.x >> 6;
    int lane = threadIdx.x & 63;
    int n = blockIdx.x * 4 + wave;
    if (n >= NODES) return;
    float4 acc = make_float4(0.f, 0.f, 0.f, 0.f);
    int e0 = rowstart[n], e1 = rowstart[n + 1];
    int e = e0;
#define A1_STEP(q, qv)                                                        \
    {                                                                         \
        float w = __int_as_float((q).y);                                      \
        f32x2 lo = __builtin_amdgcn_cvt_pk_f32_fp8((int)(qv), false);         \
        f32x2 hi = __builtin_amdgcn_cvt_pk_f32_fp8((int)(qv), true);          \
        acc.x = fmaf(w, lo[0], acc.x);                                        \
        acc.y = fmaf(w, lo[1], acc.y);                                        \
        acc.z = fmaf(w, hi[0], acc.z);                                        \
        acc.w = fmaf(w, hi[1], acc.w);                                        \
    }
    for (; e + 8 <= e1; e += 8) {
        int2 q0 = er[e],     q1 = er[e + 1], q2 = er[e + 2], q3 = er[e + 3];
        int2 q4 = er[e + 4], q5 = er[e + 5], q6 = er[e + 6], q7 = er[e + 7];
        uint v0 = *(const uint*)(h8 + (size_t)q0.x * 256 + lane * 4);
        uint v1 = *(const uint*)(h8 + (size_t)q1.x * 256 + lane * 4);
        uint v2 = *(const uint*)(h8 + (size_t)q2.x * 256 + lane * 4);
        uint v3 = *(const uint*)(h8 + (size_t)q3.x * 256 + lane * 4);
        uint v4 = *(const uint*)(h8 + (size_t)q4.x * 256 + lane * 4);
        uint v5 = *(const uint*)(h8 + (size_t)q5.x * 256 + lane * 4);
        uint v6 = *(const uint*)(h8 + (size_t)q6.x * 256 + lane * 4);
        uint v7 = *(const uint*)(h8 + (size_t)q7.x * 256 + lane * 4);
        A1_STEP(q0, v0) A1_STEP(q1, v1) A1_STEP(q2, v2) A1_STEP(q3, v3)
        A1_STEP(q4, v4) A1_STEP(q5, v5) A1_STEP(q6, v6) A1_STEP(q7, v7)
    }
    for (; e < e1; ++e) {
        int2 q = er[e];
        uint v = *(const uint*)(h8 + (size_t)q.x * 256 + lane * 4);
        A1_STEP(q, v)
    }
#undef A1_STEP
    float dn = dinv[n];
    float s2 = dn * dn;
    uint qs = *(const uint*)(h8 + (size_t)n * 256 + lane * 4);
    f32x2 slo = __builtin_amdgcn_cvt_pk_f32_fp8((int)qs, false);
    f32x2 shi = __builtin_amdgcn_cvt_pk_f32_fp8((int)qs, true);
    float4 bb = *(const float4*)(b1 + lane * 4);
    ushort4 r;
    r.x = f2bf(fmaxf(fmaf(acc.x, dn, fmaf(slo[0], s2, bb.x)), 0.f));
    r.y = f2bf(fmaxf(fmaf(acc.y, dn, fmaf(slo[1], s2, bb.y)), 0.f));
    r.z = f2bf(fmaxf(fmaf(acc.z, dn, fmaf(shi[0], s2, bb.z)), 0.f));
    r.w = f2bf(fmaxf(fmaf(acc.w, dn, fmaf(shi[1], s2, bb.w)), 0.f));
    *(ushort4*)(out + (size_t)n * 256 + lane * 4) = r;
}

// ---------------- layer-2 aggregation + bias + log_softmax (bf16 h2) ----------------
__global__ __launch_bounds__(256) void k_agg2(const ushort* __restrict__ h,
                                              const int* __restrict__ rowstart,
                                              const int2* __restrict__ er,
                                              const float* __restrict__ dinv,
                                              const float* __restrict__ b2,
                                              float* __restrict__ out) {
    int wave = threadIdx.x >> 6;
    int lane = threadIdx.x & 63;
    int n = blockIdx.x * 4 + wave;
    if (n >= NODES) return;
    float acc = 0.f;
    int e0 = rowstart[n], e1 = rowstart[n + 1];
    int e = e0;
    for (; e + 8 <= e1; e += 8) {
        int2 q0 = er[e],     q1 = er[e + 1], q2 = er[e + 2], q3 = er[e + 3];
        int2 q4 = er[e + 4], q5 = er[e + 5], q6 = er[e + 6], q7 = er[e + 7];
        ushort v0 = h[(size_t)q0.x * 64 + lane];
        ushort v1 = h[(size_t)q1.x * 64 + lane];
        ushort v2 = h[(size_t)q2.x * 64 + lane];
        ushort v3 = h[(size_t)q3.x * 64 + lane];
        ushort v4 = h[(size_t)q4.x * 64 + lane];
        ushort v5 = h[(size_t)q5.x * 64 + lane];
        ushort v6 = h[(size_t)q6.x * 64 + lane];
        ushort v7 = h[(size_t)q7.x * 64 + lane];
        acc = fmaf(__int_as_float(q0.y), bf2f(v0), acc);
        acc = fmaf(__int_as_float(q1.y), bf2f(v1), acc);
        acc = fmaf(__int_as_float(q2.y), bf2f(v2), acc);
        acc = fmaf(__int_as_float(q3.y), bf2f(v3), acc);
        acc = fmaf(__int_as_float(q4.y), bf2f(v4), acc);
        acc = fmaf(__int_as_float(q5.y), bf2f(v5), acc);
        acc = fmaf(__int_as_float(q6.y), bf2f(v6), acc);
        acc = fmaf(__int_as_float(q7.y), bf2f(v7), acc);
    }
    for (; e < e1; ++e) {
        int2 q = er[e];
        acc = fmaf(__int_as_float(q.y), bf2f(h[(size_t)q.x * 64 + lane]), acc);
    }
    float dn = dinv[n];
    float r = fmaf(acc, dn, fmaf(bf2f(h[(size_t)n * 64 + lane]), dn * dn, b2[lane]));
    float m = r;
#pragma unroll
    for (int off = 32; off; off >>= 1) m = fmaxf(m, __shfl_xor(m, off));
    float ex = __expf(r - m);
    float ssum = ex;
#pragma unroll
    for (int off = 32; off; off >>= 1) ssum += __shfl_xor(ssum, off);
    out[(size_t)n * 64 + lane] = r - m - __logf(ssum);
}

// ---------------- launch ----------------

extern "C" void kernel_launch(void* const* d_in, const int* in_sizes, int n_in,
                              void* d_out, int out_size, void* d_ws, size_t ws_size,
                              hipStream_t stream) {
    const float* x  = (const float*)d_in[0];
    const float* W1 = (const float*)d_in[1];
    const float* b1 = (const float*)d_in[2];
    const float* W2 = (const float*)d_in[3];
    const float* b2 = (const float*)d_in[4];
    const int*   ei = (const int*)d_in[5];
    int E = in_sizes[5] / 2;
    const int* src = ei;
    const int* dst = ei + E;
    float* out = (float*)d_out;

    char* wsp = (char*)d_ws;
    auto alloc = [&](size_t bytes) {
        char* p = wsp;
        wsp += (bytes + 255) & ~(size_t)255;
        return p;
    };
    int*    degcnt   = (int*)alloc((size_t)NODES * 4);
    float*  dinv     = (float*)alloc((size_t)NODES * 4);
    int*    rowstart = (int*)alloc((size_t)(NODES + 1) * 4);
    int*    cursor   = (int*)alloc((size_t)NODES * 4);
    int*    bsum     = (int*)alloc((size_t)NB * 4);
    int*    boff     = (int*)alloc((size_t)NB * 4);
    int2*   erec     = (int2*)alloc((size_t)E * 8);
    ushort* w1t      = (ushort*)alloc((size_t)256 * 512 * 2);   // W1^T bf16 [256][512]
    ushort* w2t      = (ushort*)alloc((size_t)64 * 256 * 2);    // W2^T bf16 [64][256]
    uchar*  h1f8     = (uchar*)alloc((size_t)NODES * 256);      // fp8 h1 (12.8 MB)
    ushort* h1ab     = (ushort*)alloc((size_t)NODES * 256 * 2); // bf16 relu(agg1)
    ushort* h2b      = (ushort*)alloc((size_t)NODES * 64 * 2);  // bf16 h2

    hipMemsetAsync(degcnt, 0, (size_t)NODES * 4, stream);
    hipMemsetAsync(cursor, 0, (size_t)NODES * 4, stream);

    k_count<<<(E + 255) / 256, 256, 0, stream>>>(dst, E, degcnt);
    k_bsum<<<NB, 256, 0, stream>>>(degcnt, bsum);
    k_bscan<<<1, 256, 0, stream>>>(bsum, boff, NB);
    k_scan3<<<NB, 256, 0, stream>>>(degcnt, boff, rowstart, dinv);
    k_scatter<<<(E + 255) / 256, 256, 0, stream>>>(src, dst, E, rowstart, cursor, dinv, erec);

    // weight casts (tiny)
    k_castT<<<(512 * 256 + 255) / 256, 256, 0, stream>>>(W1, w1t, 512, 256);
    k_castT<<<(256 * 64 + 255) / 256, 256, 0, stream>>>(W2, w2t, 256, 64);

    // layer 1: h1 = x @ W1 (x read once, BN=256) -> fp8 e4m3
    k_gemm<64, 256, 1, 4, true, 2><<<dim3((NODES + 63) / 64, 1), 256, 0, stream>>>(
        x, nullptr, w1t, nullptr, nullptr, h1f8, NODES, 256, 512);
    k_agg1<<<(NODES + 3) / 4, 256, 0, stream>>>(h1f8, rowstart, erec, dinv, b1, h1ab);

    // layer 2: h2 = h1a @ W2 -> bf16
    k_gemm<64, 64, 4, 1, false, 1><<<dim3((NODES + 63) / 64, 1), 256, 0, stream>>>(
        nullptr, h1ab, w2t, nullptr, h2b, nullptr, NODES, 64, 256);
    k_agg2<<<(NODES + 3) / 4, 256, 0, stream>>>(h2b, rowstart, erec, dinv, b2, out);
}